// Round 8
// baseline (445.449 us; speedup 1.0000x reference)
//
#include <hip/hip_runtime.h>
#include <hip/hip_bf16.h>
#include <hip/hip_fp16.h>

// CompressedFP8Linear: out[128,8192] = x[128,8192] @ (w*scale)[8192,8192]^T + bias
//
// R8 journal:
//  - R7: 418us total (kernels ~155us combined; profile top-5 clogged by the
//    harness's 1GB ws-poison fills at 160us). Cycle model of R7 gemm: vmcnt
//    FIFO couples x-frag consumption to older W HBM prefetch (~900cyc), and
//    VGPR cap (128) likely serialized the per-ss x loads -> latency chain.
//  - R8: NO LDS, NO barrier, NO lgkmcnt in the gemm. B(w) fragments loaded
//    DIRECTLY from global in MFMA layout (2x dwordx4/lane, full 128B lines,
//    weight read exactly once); A(x) from prep-swizzled bf16 ws (L2-hot).
//    Symmetric 1-step register double buffer -> uniform vmcnt(8).
//    Wave = 32n x 64m; block = 4 independent waves; 1024 blocks, 4/CU.
//  - Input ID (R4-verified): size-RANK largest=weight, 2nd=x; scale/bias +
//    bias dtype resolved in prep via ballot probes into ws.
//  - Floor: 268 MB / 6.3 TB/s ~= 43 us.

namespace {
constexpr int MM = 128;
constexpr int NN = 8192;
constexpr int KK = 8192;
constexpr int KSPLIT = 8;
constexpr int KPB = KK / KSPLIT;     // 1024 k per kz
constexpr int NSS = KPB / 32;        // 32 k-steps of 32 per kz

constexpr size_t WS_SCALE_OFF = 0;                    // 8192 f32
constexpr size_t WS_BIAS_OFF  = 8192 * 4;             // 8192 f32
constexpr size_t WS_XSW_OFF   = 65536;                // 2 MB bf16 swizzled x
constexpr size_t WS_NEED      = WS_XSW_OFF + (size_t)MM * KK * 2;

typedef __attribute__((ext_vector_type(8))) short bf16x8;
typedef __attribute__((ext_vector_type(4))) float f32x4;
}

// ---------------- prep: resolve scale/bias + swizzle x -> A-frag bf16 ----------------
// x_sw layout: uint4 index ((s*8 + t)*64 + l) holds A[m=16t+(l&15)][k=32s+(l>>4)*8+j],
// j=0..7 (exactly the 16x16x32 A-fragment lane l needs for m-tile t, k-step s).
__global__ __launch_bounds__(256)
void cfp8_prep(const float* __restrict__ x,
               const float* __restrict__ c1, const float* __restrict__ c2,
               unsigned char* __restrict__ ws)
{
    const int bid = blockIdx.x;
    const int tid = threadIdx.x;

    if (bid < 32) {
        __shared__ int s_c1s, s_kind;
        if (tid < 64) {
            float v = c1[tid * 64];
            unsigned long long b = __ballot((v > 1e-4f) && (v < 0.5f));
            int c1s = (b == ~0ull) ? 1 : 0;
            const void* bp = c1s ? (const void*)c2 : (const void*)c1;
            float vf = __half2float(((const __half*)bp)[tid * 64]);
            unsigned long long bf_ = __ballot((vf < 0.5f) && (vf > -0.5f));
            float vb = __bfloat162float(((const __hip_bfloat16*)bp)[tid * 64]);
            unsigned long long bb = __ballot((vb < 0.5f) && (vb > -0.5f));
            if (tid == 0) {
                s_c1s  = c1s;
                s_kind = (bf_ == ~0ull) ? 0 : ((bb == ~0ull) ? 1 : 2);
            }
        }
        __syncthreads();
        const float* scalep = s_c1s ? c1 : c2;
        const void*  biasp  = s_c1s ? (const void*)c2 : (const void*)c1;
        const int i = bid * 256 + tid;              // [0, 8192)
        float bsv;
        if (s_kind == 0)      bsv = __half2float(((const __half*)biasp)[i]);
        else if (s_kind == 1) bsv = __bfloat162float(((const __hip_bfloat16*)biasp)[i]);
        else                  bsv = ((const float*)biasp)[i];
        ((float*)(ws + WS_SCALE_OFF))[i] = scalep[i];
        ((float*)(ws + WS_BIAS_OFF))[i]  = bsv;
    } else {
        const int g = (bid - 32) * 256 + tid;       // [0, 131072)
        const float4* src = (const float4*)x + (size_t)g * 2;
        float4 a = src[0], b = src[1];
        const int m  = g >> 10;
        const int kg = g & 1023;
        const int s  = kg >> 2;
        const int r8 = kg & 3;
        const int t  = m >> 4;
        const int lm = m & 15;
        const int l  = r8 * 16 + lm;
        union { __hip_bfloat16 h[8]; uint4 u; } p;
        p.h[0] = __float2bfloat16(a.x); p.h[1] = __float2bfloat16(a.y);
        p.h[2] = __float2bfloat16(a.z); p.h[3] = __float2bfloat16(a.w);
        p.h[4] = __float2bfloat16(b.x); p.h[5] = __float2bfloat16(b.y);
        p.h[6] = __float2bfloat16(b.z); p.h[7] = __float2bfloat16(b.w);
        ((uint4*)(ws + WS_XSW_OFF))[(size_t)(s * 8 + t) * 64 + l] = p.u;
    }
}

// ---------------- GEMM: zero-LDS, barrier-free, register-pipelined ----------------
__global__ __launch_bounds__(256, 4)
void cfp8_gemm2(const float* __restrict__ w, const unsigned char* __restrict__ ws,
                float* __restrict__ out)
{
    const int tid  = threadIdx.x;
    const int lane = tid & 63;
    const int wid  = tid >> 6;
    const int nsub = wid & 1;            // n-half within block
    const int msub = wid >> 1;           // m-half (0: rows 0-63, 1: 64-127)
    const int kz   = blockIdx.y;
    const int n0w  = blockIdx.x * 64 + nsub * 32;   // wave's 32 n-rows
    const size_t kbase = (size_t)kz * KPB;

    const uint4* xsw4 = (const uint4*)(ws + WS_XSW_OFF);
    const float* wsc  = (const float*)(ws + WS_SCALE_OFF);
    const float* wbs  = (const float*)(ws + WS_BIAS_OFF);

    const int l16  = lane & 15;
    const int quad = lane >> 4;

    // epilogue params (plain loads, consumed at the end)
    const float sc0 = wsc[n0w + l16];
    const float sc1 = wsc[n0w + 16 + l16];
    const float bs0 = (kz == 0) ? wbs[n0w + l16] : 0.0f;
    const float bs1 = (kz == 0) ? wbs[n0w + 16 + l16] : 0.0f;

    // B(w) fragment pointers: lane reads w[n0w + j*16 + l16][k + quad*8 .. +7]
    const float* wr0 = w + (size_t)(n0w + l16) * KK + kbase + quad * 8;
    const float* wr1 = wr0 + (size_t)16 * KK;

    // A(x) fragment base: k-step sg, m-tile t -> xsw4[sg*512 + (msub*4+t)*64 + lane]
    const int sg0 = kz * NSS;
    const uint4* xb = xsw4 + (size_t)sg0 * 512 + (size_t)(msub * 4) * 64 + lane;

    float4 wfb[2][2][2];   // [buf][n-frag j][half]  (fp32, cvt at use)
    uint4  afb[2][4];      // [buf][m-tile t]        (bf16 frags)

#define LOAD_B(buf, s)                                                   \
    do {                                                                 \
        wfb[buf][0][0] = *(const float4*)(wr0 + (s) * 32);               \
        wfb[buf][0][1] = *(const float4*)(wr0 + (s) * 32 + 4);           \
        wfb[buf][1][0] = *(const float4*)(wr1 + (s) * 32);               \
        wfb[buf][1][1] = *(const float4*)(wr1 + (s) * 32 + 4);           \
    } while (0)
#define LOAD_A(buf, s)                                                   \
    do {                                                                 \
        const uint4* xp = xb + (size_t)(s) * 512;                        \
        afb[buf][0] = xp[0];                                             \
        afb[buf][1] = xp[64];                                            \
        afb[buf][2] = xp[128];                                           \
        afb[buf][3] = xp[192];                                           \
    } while (0)

    LOAD_B(0, 0);
    LOAD_A(0, 0);

    f32x4 acc[4][2];
#pragma unroll
    for (int t = 0; t < 4; ++t) {
        acc[t][0] = (f32x4){0.f, 0.f, 0.f, 0.f};
        acc[t][1] = (f32x4){0.f, 0.f, 0.f, 0.f};
    }

#pragma unroll 2
    for (int s = 0; s < NSS; ++s) {
        const int buf = s & 1;
        const int nxt = buf ^ 1;
        const int sn = (s + 1 < NSS) ? (s + 1) : 0;   // tail reload: harmless

        LOAD_B(nxt, sn);
        LOAD_A(nxt, sn);

        // cvt current B frags fp32 -> bf16 (vmcnt(8): waits only buf's loads)
        bf16x8 bw[2];
#pragma unroll
        for (int j = 0; j < 2; ++j) {
            union { __hip_bfloat16 h[8]; bf16x8 v; } p;
            const float* f = (const float*)&wfb[buf][j][0];
#pragma unroll
            for (int i = 0; i < 8; ++i) p.h[i] = __float2bfloat16(f[i]);
            bw[j] = p.v;
        }

#pragma unroll
        for (int t = 0; t < 4; ++t) {
            bf16x8 af = *(bf16x8*)&afb[buf][t];
            acc[t][0] = __builtin_amdgcn_mfma_f32_16x16x32_bf16(af, bw[0], acc[t][0], 0, 0, 0);
            acc[t][1] = __builtin_amdgcn_mfma_f32_16x16x32_bf16(af, bw[1], acc[t][1], 0, 0, 0);
        }
    }
#undef LOAD_A
#undef LOAD_B

    // epilogue: scale, bias (kz==0), atomic combine over KSPLIT
#pragma unroll
    for (int t = 0; t < 4; ++t) {
        const int mb = msub * 64 + t * 16 + quad * 4;
#pragma unroll
        for (int r = 0; r < 4; ++r) {
            float* o = out + (size_t)(mb + r) * NN + n0w;
            atomicAdd(o + l16,      acc[t][0][r] * sc0 + bs0);
            atomicAdd(o + 16 + l16, acc[t][1][r] * sc1 + bs1);
        }
    }
}

// ---------------- fallback (R6, passing): used only if ws too small ----------------
namespace fb {
constexpr int NT = 64;
constexpr int KTf = 32;
constexpr int NITf = KPB / KTf;
constexpr int LDSP = KTf + 8;
}

__global__ __launch_bounds__(256, 4)
void cfp8lin_mfma2(const float* __restrict__ x, const float* __restrict__ w,
                   const float* __restrict__ c1, const float* __restrict__ c2,
                   float* __restrict__ out)
{
    using namespace fb;
    __shared__ __align__(16) __hip_bfloat16 lx[2][MM * LDSP];
    __shared__ __align__(16) __hip_bfloat16 lw[2][NT * LDSP];
    __shared__ float s_scale[NT];
    __shared__ float s_bias[NT];
    __shared__ int s_c1_is_scale;
    __shared__ int s_bias_kind;

    const int tid = threadIdx.x;
    const int n0 = blockIdx.x * NT;
    const int kz = blockIdx.y;
    const size_t kbase = (size_t)kz * KPB;

    if (tid < 64) {
        float v = c1[tid * 64];
        unsigned long long b = __ballot((v > 1e-4f) && (v < 0.5f));
        int c1s = (b == ~0ull) ? 1 : 0;
        const void* bp = c1s ? (const void*)c2 : (const void*)c1;
        float vf = __half2float(((const __half*)bp)[tid * 64]);
        unsigned long long bf_ = __ballot((vf < 0.5f) && (vf > -0.5f));
        float vb = __bfloat162float(((const __hip_bfloat16*)bp)[tid * 64]);
        unsigned long long bb = __ballot((vb < 0.5f) && (vb > -0.5f));
        if (tid == 0) {
            s_c1_is_scale = c1s;
            s_bias_kind = (bf_ == ~0ull) ? 0 : ((bb == ~0ull) ? 1 : 2);
        }
    }

    const int lrow = tid >> 3;
    const int lc4  = tid & 7;
    const float* xg = x + (size_t)lrow * KK + kbase + lc4 * 4;
    const float* wg = w + (size_t)(n0 + lrow) * KK + kbase + lc4 * 4;

    float4 xv[4], wv[2];
    auto load_tile = [&](int kt) {
        const size_t ko = (size_t)kt * KTf;
#pragma unroll
        for (int i = 0; i < 4; ++i)
            xv[i] = *(const float4*)(xg + (size_t)(i * 32) * KK + ko);
#pragma unroll
        for (int i = 0; i < 2; ++i)
            wv[i] = *(const float4*)(wg + (size_t)(i * 32) * KK + ko);
    };
    load_tile(0);

    const int lane = tid & 63;
    const int wid  = tid >> 6;
    const int wm0  = wid * 32;
    const int l16  = lane & 15;
    const int quad = lane >> 4;
    const int kcol = quad * 8;

    f32x4 acc[2][4];
#pragma unroll
    for (int i = 0; i < 2; ++i)
#pragma unroll
        for (int j = 0; j < 4; ++j) acc[i][j] = (f32x4){0.f, 0.f, 0.f, 0.f};

    for (int kt = 0; kt < NITf; ++kt) {
        const int buf = kt & 1;
#pragma unroll
        for (int i = 0; i < 4; ++i) {
            union { __hip_bfloat16 b[4]; uint2 u; } p;
            p.b[0] = __float2bfloat16(xv[i].x); p.b[1] = __float2bfloat16(xv[i].y);
            p.b[2] = __float2bfloat16(xv[i].z); p.b[3] = __float2bfloat16(xv[i].w);
            *(uint2*)&lx[buf][(i * 32 + lrow) * LDSP + lc4 * 4] = p.u;
        }
#pragma unroll
        for (int i = 0; i < 2; ++i) {
            union { __hip_bfloat16 b[4]; uint2 u; } p;
            p.b[0] = __float2bfloat16(wv[i].x); p.b[1] = __float2bfloat16(wv[i].y);
            p.b[2] = __float2bfloat16(wv[i].z); p.b[3] = __float2bfloat16(wv[i].w);
            *(uint2*)&lw[buf][(i * 32 + lrow) * LDSP + lc4 * 4] = p.u;
        }
        load_tile((kt + 1 < NITf) ? (kt + 1) : 0);
        __syncthreads();
        bf16x8 af[2], bw[4];
#pragma unroll
        for (int i = 0; i < 2; ++i)
            af[i] = *(const bf16x8*)&lx[buf][(wm0 + i * 16 + l16) * LDSP + kcol];
#pragma unroll
        for (int j = 0; j < 4; ++j)
            bw[j] = *(const bf16x8*)&lw[buf][(j * 16 + l16) * LDSP + kcol];
#pragma unroll
        for (int i = 0; i < 2; ++i)
#pragma unroll
            for (int j = 0; j < 4; ++j)
                acc[i][j] = __builtin_amdgcn_mfma_f32_16x16x32_bf16(
                    af[i], bw[j], acc[i][j], 0, 0, 0);
    }

    __syncthreads();
    const float* scalep = s_c1_is_scale ? c1 : c2;
    const void*  biasp  = s_c1_is_scale ? (const void*)c2 : (const void*)c1;
    if (tid < fb::NT) {
        s_scale[tid] = scalep[n0 + tid];
        float b = 0.0f;
        if (kz == 0) {
            if (s_bias_kind == 0)      b = __half2float(((const __half*)biasp)[n0 + tid]);
            else if (s_bias_kind == 1) b = __bfloat162float(((const __hip_bfloat16*)biasp)[n0 + tid]);
            else                       b = ((const float*)biasp)[n0 + tid];
        }
        s_bias[tid] = b;
    }
    __syncthreads();

#pragma unroll
    for (int j = 0; j < 4; ++j) {
        const int nl = j * 16 + l16;
        const float scv = s_scale[nl];
        const float bsv = s_bias[nl];
#pragma unroll
        for (int i = 0; i < 2; ++i) {
            const int mb = wm0 + i * 16 + quad * 4;
#pragma unroll
            for (int r = 0; r < 4; ++r)
                atomicAdd(out + (size_t)(mb + r) * NN + n0 + nl,
                          acc[i][j][r] * scv + bsv);
        }
    }
}

extern "C" void kernel_launch(void* const* d_in, const int* in_sizes, int n_in,
                              void* d_out, int out_size, void* d_ws, size_t ws_size,
                              hipStream_t stream) {
    // Size-RANK input ID (R4-verified): largest = weight, 2nd = x,
    // remaining two = {scale, bias} (disambiguated on device).
    int iw = 0;
    for (int i = 1; i < n_in; ++i) if (in_sizes[i] > in_sizes[iw]) iw = i;
    int ix = -1;
    for (int i = 0; i < n_in; ++i)
        if (i != iw && (ix < 0 || in_sizes[i] > in_sizes[ix])) ix = i;
    const float* c1 = nullptr;
    const float* c2 = nullptr;
    for (int i = 0; i < n_in; ++i) {
        if (i == iw || i == ix) continue;
        if (!c1) c1 = (const float*)d_in[i];
        else     c2 = (const float*)d_in[i];
    }
    const float* w = (const float*)d_in[iw];
    const float* x = (const float*)d_in[ix];
    float* out = (float*)d_out;

    hipMemsetAsync(d_out, 0, (size_t)out_size * sizeof(float), stream);

    if (ws_size >= WS_NEED && d_ws != nullptr) {
        unsigned char* ws = (unsigned char*)d_ws;
        cfp8_prep<<<dim3(32 + 512), dim3(256), 0, stream>>>(x, c1, c2, ws);
        cfp8_gemm2<<<dim3(NN / 64, KSPLIT), dim3(256), 0, stream>>>(w, ws, out);
    } else {
        dim3 grid(NN / fb::NT, KSPLIT);
        cfp8lin_mfma2<<<grid, dim3(256), 0, stream>>>(x, w, c1, c2, out);
    }
}

// Round 9
// 426.275 us; speedup vs baseline: 1.0450x; 1.0450x over previous
//
#include <hip/hip_runtime.h>
#include <hip/hip_bf16.h>
#include <hip/hip_fp16.h>

// CompressedFP8Linear: out[128,8192] = x[128,8192] @ (w*scale)[8192,8192]^T + bias
//
// R9 journal:
//  - R5/R6/R7/R8 all plateau ~176us despite different structures. Unifying
//    model: per-CU VMEM segment throughput. R8 segment count dominated by
//    8.4M atomicAdds (~33k segs/CU) + 512MB x re-reads + 2x-split w frags.
//  - R9: (1) atomics -> coalesced per-kz partial STORES into ws + reduce
//    kernel (sum 8 partials + bias); (2) 128x128 block (R5-verified quadrant
//    waves) halves x traffic; (3) B-frags as 2 back-to-back dwordx4 covering
//    full 128B lines; A-frags 1KB-contiguous from prep-swizzled ws.
//  - Fragment math carried from PASSING kernels only (R8 B-from-global,
//    R5 quadrant epilogue, R7/R8 prep).
//  - Floor: 268 MB / 6.3 TB/s ~= 43 us + ~31 us segment cost.

namespace {
constexpr int MM = 128;
constexpr int NN = 8192;
constexpr int KK = 8192;
constexpr int KSPLIT = 8;
constexpr int KPB = KK / KSPLIT;     // 1024 k per kz
constexpr int NSS = KPB / 32;        // 32 k-steps of 32

constexpr size_t WS_SCALE_OFF = 0;                        // 8192 f32
constexpr size_t WS_BIAS_OFF  = 8192 * 4;                 // 8192 f32
constexpr size_t WS_XSW_OFF   = 65536;                    // 2 MB bf16 swizzled x
constexpr size_t WS_PART_OFF  = WS_XSW_OFF + (size_t)MM * KK * 2;   // 8 x 4 MB partials
constexpr size_t WS_NEED      = WS_PART_OFF + (size_t)KSPLIT * MM * NN * 4;

typedef __attribute__((ext_vector_type(8))) short bf16x8;
typedef __attribute__((ext_vector_type(4))) float f32x4;
}

// ---------------- prep: resolve scale/bias + swizzle x -> A-frag bf16 ----------------
// x_sw: uint4 index ((s*8 + t)*64 + l) holds A[m=16t+(l&15)][k=32s+(l>>4)*8+j], j=0..7.
__global__ __launch_bounds__(256)
void cfp8_prep(const float* __restrict__ x,
               const float* __restrict__ c1, const float* __restrict__ c2,
               unsigned char* __restrict__ ws)
{
    const int bid = blockIdx.x;
    const int tid = threadIdx.x;

    if (bid < 32) {
        __shared__ int s_c1s, s_kind;
        if (tid < 64) {
            float v = c1[tid * 64];
            unsigned long long b = __ballot((v > 1e-4f) && (v < 0.5f));
            int c1s = (b == ~0ull) ? 1 : 0;
            const void* bp = c1s ? (const void*)c2 : (const void*)c1;
            float vf = __half2float(((const __half*)bp)[tid * 64]);
            unsigned long long bf_ = __ballot((vf < 0.5f) && (vf > -0.5f));
            float vb = __bfloat162float(((const __hip_bfloat16*)bp)[tid * 64]);
            unsigned long long bb = __ballot((vb < 0.5f) && (vb > -0.5f));
            if (tid == 0) {
                s_c1s  = c1s;
                s_kind = (bf_ == ~0ull) ? 0 : ((bb == ~0ull) ? 1 : 2);
            }
        }
        __syncthreads();
        const float* scalep = s_c1s ? c1 : c2;
        const void*  biasp  = s_c1s ? (const void*)c2 : (const void*)c1;
        const int i = bid * 256 + tid;
        float bsv;
        if (s_kind == 0)      bsv = __half2float(((const __half*)biasp)[i]);
        else if (s_kind == 1) bsv = __bfloat162float(((const __hip_bfloat16*)biasp)[i]);
        else                  bsv = ((const float*)biasp)[i];
        ((float*)(ws + WS_SCALE_OFF))[i] = scalep[i];
        ((float*)(ws + WS_BIAS_OFF))[i]  = bsv;
    } else {
        const int g = (bid - 32) * 256 + tid;       // [0, 131072)
        const float4* src = (const float4*)x + (size_t)g * 2;
        float4 a = src[0], b = src[1];
        const int m  = g >> 10;
        const int kg = g & 1023;
        const int s  = kg >> 2;
        const int r8 = kg & 3;
        const int t  = m >> 4;
        const int lm = m & 15;
        const int l  = r8 * 16 + lm;
        union { __hip_bfloat16 h[8]; uint4 u; } p;
        p.h[0] = __float2bfloat16(a.x); p.h[1] = __float2bfloat16(a.y);
        p.h[2] = __float2bfloat16(a.z); p.h[3] = __float2bfloat16(a.w);
        p.h[4] = __float2bfloat16(b.x); p.h[5] = __float2bfloat16(b.y);
        p.h[6] = __float2bfloat16(b.z); p.h[7] = __float2bfloat16(b.w);
        ((uint4*)(ws + WS_XSW_OFF))[(size_t)(s * 8 + t) * 64 + l] = p.u;
    }
}

// ---------------- GEMM: 128x128 block, partial stores (no atomics) ----------------
__global__ __launch_bounds__(256, 2)
void cfp8_gemm3(const float* __restrict__ w, unsigned char* __restrict__ ws)
{
    const int tid  = threadIdx.x;
    const int lane = tid & 63;
    const int wid  = tid >> 6;
    const int wm0  = (wid & 1) * 64;     // quadrant (R5-verified)
    const int wn0  = (wid >> 1) * 64;
    const int kz   = blockIdx.y;
    const int n0   = blockIdx.x * 128;
    const size_t kbase = (size_t)kz * KPB;

    const uint4* xsw4 = (const uint4*)(ws + WS_XSW_OFF);
    const float* wsc  = (const float*)(ws + WS_SCALE_OFF);

    const int l16  = lane & 15;
    const int quad = lane >> 4;

    // B(w) row pointers: lane covers row (n0+wn0+j*16+l16), 32B chunk at quad*8
    const float* wr[4];
#pragma unroll
    for (int j = 0; j < 4; ++j)
        wr[j] = w + (size_t)(n0 + wn0 + j * 16 + l16) * KK + kbase + quad * 8;

    // A(x) base: k-step sg, m-tile t -> xsw4[sg*512 + t*64 + lane]
    const uint4* xb = xsw4 + (size_t)(kz * NSS) * 512 + (size_t)(wm0 / 16) * 64 + lane;

    f32x4 acc[4][4];
#pragma unroll
    for (int i = 0; i < 4; ++i)
#pragma unroll
        for (int j = 0; j < 4; ++j)
            acc[i][j] = (f32x4){0.f, 0.f, 0.f, 0.f};

    for (int ss = 0; ss < NSS; ++ss) {
        // A fragments (contiguous 1KB per load, L2-hot)
        const uint4* xp = xb + (size_t)ss * 512;
        uint4 a0 = xp[0], a1 = xp[64], a2 = xp[128], a3 = xp[192];

        // B fragments: 2 back-to-back dwordx4 per lane -> full 128B line/row
        bf16x8 bw[4];
#pragma unroll
        for (int j = 0; j < 4; ++j) {
            float4 b0 = *(const float4*)(wr[j] + ss * 32);
            float4 b1 = *(const float4*)(wr[j] + ss * 32 + 4);
            union { __hip_bfloat16 h[8]; bf16x8 v; } p;
            p.h[0] = __float2bfloat16(b0.x); p.h[1] = __float2bfloat16(b0.y);
            p.h[2] = __float2bfloat16(b0.z); p.h[3] = __float2bfloat16(b0.w);
            p.h[4] = __float2bfloat16(b1.x); p.h[5] = __float2bfloat16(b1.y);
            p.h[6] = __float2bfloat16(b1.z); p.h[7] = __float2bfloat16(b1.w);
            bw[j] = p.v;
        }

        bf16x8 af[4];
        af[0] = *(bf16x8*)&a0; af[1] = *(bf16x8*)&a1;
        af[2] = *(bf16x8*)&a2; af[3] = *(bf16x8*)&a3;

#pragma unroll
        for (int i = 0; i < 4; ++i)
#pragma unroll
            for (int j = 0; j < 4; ++j)
                acc[i][j] = __builtin_amdgcn_mfma_f32_16x16x32_bf16(
                    af[i], bw[j], acc[i][j], 0, 0, 0);
    }

    // ---- epilogue: scale, plain coalesced stores into per-kz partial plane ----
    float* part = (float*)(ws + WS_PART_OFF) + (size_t)kz * MM * NN;
#pragma unroll
    for (int j = 0; j < 4; ++j) {
        const int nl = wn0 + j * 16 + l16;
        const float sc = wsc[n0 + nl];
#pragma unroll
        for (int i = 0; i < 4; ++i) {
            const int mb = wm0 + i * 16 + quad * 4;
#pragma unroll
            for (int r = 0; r < 4; ++r)
                part[(size_t)(mb + r) * NN + n0 + nl] = acc[i][j][r] * sc;
        }
    }
}

// ---------------- reduce: sum 8 partials + bias -> out ----------------
__global__ __launch_bounds__(256)
void cfp8_reduce(const unsigned char* __restrict__ ws, float* __restrict__ out)
{
    const int e4 = blockIdx.x * 256 + threadIdx.x;      // [0, 262144) float4s
    const float4* p = (const float4*)(ws + WS_PART_OFF);
    float4 s = p[e4];
#pragma unroll
    for (int kz = 1; kz < KSPLIT; ++kz) {
        float4 v = p[(size_t)kz * (MM * NN / 4) + e4];
        s.x += v.x; s.y += v.y; s.z += v.z; s.w += v.w;
    }
    const float4 b = ((const float4*)(ws + WS_BIAS_OFF))[e4 & (NN / 4 - 1)];
    s.x += b.x; s.y += b.y; s.z += b.z; s.w += b.w;
    ((float4*)out)[e4] = s;
}

// ---------------- fallback (R6, passing): used only if ws too small ----------------
namespace fb {
constexpr int NT = 64;
constexpr int KTf = 32;
constexpr int NITf = KPB / KTf;
constexpr int LDSP = KTf + 8;
}

__global__ __launch_bounds__(256, 4)
void cfp8lin_mfma2(const float* __restrict__ x, const float* __restrict__ w,
                   const float* __restrict__ c1, const float* __restrict__ c2,
                   float* __restrict__ out)
{
    using namespace fb;
    __shared__ __align__(16) __hip_bfloat16 lx[2][MM * LDSP];
    __shared__ __align__(16) __hip_bfloat16 lw[2][NT * LDSP];
    __shared__ float s_scale[NT];
    __shared__ float s_bias[NT];
    __shared__ int s_c1_is_scale;
    __shared__ int s_bias_kind;

    const int tid = threadIdx.x;
    const int n0 = blockIdx.x * NT;
    const int kz = blockIdx.y;
    const size_t kbase = (size_t)kz * KPB;

    if (tid < 64) {
        float v = c1[tid * 64];
        unsigned long long b = __ballot((v > 1e-4f) && (v < 0.5f));
        int c1s = (b == ~0ull) ? 1 : 0;
        const void* bp = c1s ? (const void*)c2 : (const void*)c1;
        float vf = __half2float(((const __half*)bp)[tid * 64]);
        unsigned long long bf_ = __ballot((vf < 0.5f) && (vf > -0.5f));
        float vb = __bfloat162float(((const __hip_bfloat16*)bp)[tid * 64]);
        unsigned long long bb = __ballot((vb < 0.5f) && (vb > -0.5f));
        if (tid == 0) {
            s_c1_is_scale = c1s;
            s_bias_kind = (bf_ == ~0ull) ? 0 : ((bb == ~0ull) ? 1 : 2);
        }
    }

    const int lrow = tid >> 3;
    const int lc4  = tid & 7;
    const float* xg = x + (size_t)lrow * KK + kbase + lc4 * 4;
    const float* wg = w + (size_t)(n0 + lrow) * KK + kbase + lc4 * 4;

    float4 xv[4], wv[2];
    auto load_tile = [&](int kt) {
        const size_t ko = (size_t)kt * KTf;
#pragma unroll
        for (int i = 0; i < 4; ++i)
            xv[i] = *(const float4*)(xg + (size_t)(i * 32) * KK + ko);
#pragma unroll
        for (int i = 0; i < 2; ++i)
            wv[i] = *(const float4*)(wg + (size_t)(i * 32) * KK + ko);
    };
    load_tile(0);

    const int lane = tid & 63;
    const int wid  = tid >> 6;
    const int wm0  = wid * 32;
    const int l16  = lane & 15;
    const int quad = lane >> 4;
    const int kcol = quad * 8;

    f32x4 acc[2][4];
#pragma unroll
    for (int i = 0; i < 2; ++i)
#pragma unroll
        for (int j = 0; j < 4; ++j) acc[i][j] = (f32x4){0.f, 0.f, 0.f, 0.f};

    for (int kt = 0; kt < NITf; ++kt) {
        const int buf = kt & 1;
#pragma unroll
        for (int i = 0; i < 4; ++i) {
            union { __hip_bfloat16 b[4]; uint2 u; } p;
            p.b[0] = __float2bfloat16(xv[i].x); p.b[1] = __float2bfloat16(xv[i].y);
            p.b[2] = __float2bfloat16(xv[i].z); p.b[3] = __float2bfloat16(xv[i].w);
            *(uint2*)&lx[buf][(i * 32 + lrow) * LDSP + lc4 * 4] = p.u;
        }
#pragma unroll
        for (int i = 0; i < 2; ++i) {
            union { __hip_bfloat16 b[4]; uint2 u; } p;
            p.b[0] = __float2bfloat16(wv[i].x); p.b[1] = __float2bfloat16(wv[i].y);
            p.b[2] = __float2bfloat16(wv[i].z); p.b[3] = __float2bfloat16(wv[i].w);
            *(uint2*)&lw[buf][(i * 32 + lrow) * LDSP + lc4 * 4] = p.u;
        }
        load_tile((kt + 1 < NITf) ? (kt + 1) : 0);
        __syncthreads();
        bf16x8 af[2], bw[4];
#pragma unroll
        for (int i = 0; i < 2; ++i)
            af[i] = *(const bf16x8*)&lx[buf][(wm0 + i * 16 + l16) * LDSP + kcol];
#pragma unroll
        for (int j = 0; j < 4; ++j)
            bw[j] = *(const bf16x8*)&lw[buf][(j * 16 + l16) * LDSP + kcol];
#pragma unroll
        for (int i = 0; i < 2; ++i)
#pragma unroll
            for (int j = 0; j < 4; ++j)
                acc[i][j] = __builtin_amdgcn_mfma_f32_16x16x32_bf16(
                    af[i], bw[j], acc[i][j], 0, 0, 0);
    }

    __syncthreads();
    const float* scalep = s_c1_is_scale ? c1 : c2;
    const void*  biasp  = s_c1_is_scale ? (const void*)c2 : (const void*)c1;
    if (tid < fb::NT) {
        s_scale[tid] = scalep[n0 + tid];
        float b = 0.0f;
        if (kz == 0) {
            if (s_bias_kind == 0)      b = __half2float(((const __half*)biasp)[n0 + tid]);
            else if (s_bias_kind == 1) b = __bfloat162float(((const __hip_bfloat16*)biasp)[n0 + tid]);
            else                       b = ((const float*)biasp)[n0 + tid];
        }
        s_bias[tid] = b;
    }
    __syncthreads();

#pragma unroll
    for (int j = 0; j < 4; ++j) {
        const int nl = j * 16 + l16;
        const float scv = s_scale[nl];
        const float bsv = s_bias[nl];
#pragma unroll
        for (int i = 0; i < 2; ++i) {
            const int mb = wm0 + i * 16 + quad * 4;
#pragma unroll
            for (int r = 0; r < 4; ++r)
                atomicAdd(out + (size_t)(mb + r) * NN + n0 + nl,
                          acc[i][j][r] * scv + bsv);
        }
    }
}

extern "C" void kernel_launch(void* const* d_in, const int* in_sizes, int n_in,
                              void* d_out, int out_size, void* d_ws, size_t ws_size,
                              hipStream_t stream) {
    // Size-RANK input ID (R4-verified): largest = weight, 2nd = x,
    // remaining two = {scale, bias} (disambiguated on device).
    int iw = 0;
    for (int i = 1; i < n_in; ++i) if (in_sizes[i] > in_sizes[iw]) iw = i;
    int ix = -1;
    for (int i = 0; i < n_in; ++i)
        if (i != iw && (ix < 0 || in_sizes[i] > in_sizes[ix])) ix = i;
    const float* c1 = nullptr;
    const float* c2 = nullptr;
    for (int i = 0; i < n_in; ++i) {
        if (i == iw || i == ix) continue;
        if (!c1) c1 = (const float*)d_in[i];
        else     c2 = (const float*)d_in[i];
    }
    const float* w = (const float*)d_in[iw];
    const float* x = (const float*)d_in[ix];
    float* out = (float*)d_out;

    if (ws_size >= WS_NEED && d_ws != nullptr) {
        unsigned char* ws = (unsigned char*)d_ws;
        cfp8_prep<<<dim3(32 + 512), dim3(256), 0, stream>>>(x, c1, c2, ws);
        cfp8_gemm3<<<dim3(NN / 128, KSPLIT), dim3(256), 0, stream>>>(w, ws);
        cfp8_reduce<<<dim3(MM * NN / 4 / 256), dim3(256), 0, stream>>>(ws, out);
    } else {
        hipMemsetAsync(d_out, 0, (size_t)out_size * sizeof(float), stream);
        dim3 grid(NN / fb::NT, KSPLIT);
        cfp8lin_mfma2<<<grid, dim3(256), 0, stream>>>(x, w, c1, c2, out);
    }
}